// Round 17
// baseline (1746.938 us; speedup 1.0000x reference)
//
#include <hip/hip_runtime.h>
#include <hip/hip_bf16.h>
#include <stdint.h>

// ---------------------------------------------------------------------------
// Fused MHA block: QKV proj -> attention (weights are output[1]) -> FC proj
// B=2 S=2048 E=1024 H=16 Dh=64.  All matmuls bf16 MFMA 16x16x32, fp32 accum.
// r17 = r13 (best: 264.4us) + PROFILING REP COUNTS: attn_k x3, QKV GEMM x12,
// FC GEMM x30 — all idempotent re-executions, pushing the three kernels above
// the harness's ~355us poison-fills into rocprof's top-5 so we finally see
// their counters (blocked since r2).  Score sacrificed this round for full
// attribution; r18 reverts rep=1 and acts on the counters.
// ---------------------------------------------------------------------------

typedef __attribute__((ext_vector_type(8))) short bf16x8;
typedef __attribute__((ext_vector_type(4))) short bf16x4;
typedef __attribute__((ext_vector_type(4))) float f32x4;

#define MFMA16(a, b, c) __builtin_amdgcn_mfma_f32_16x16x32_bf16(a, b, c, 0, 0, 0)
#define EXP2(x) __builtin_amdgcn_exp2f(x)

__device__ __forceinline__ short f2bf(float x) {
  uint32_t u = __builtin_bit_cast(uint32_t, x);
  u += 0x7FFFu + ((u >> 16) & 1u);   // round-to-nearest-even
  return (short)(u >> 16);
}

__device__ __forceinline__ uint32_t cvtpk_bf16(float lo, float hi) {
  uint32_t r;
  asm("v_cvt_pk_bf16_f32 %0, %1, %2" : "=v"(r) : "v"(lo), "v"(hi));
  return r;  // low 16 = lo, high 16 = hi
}

__device__ __forceinline__ void gload16(const void* g, void* l) {
  __builtin_amdgcn_global_load_lds((const __attribute__((address_space(1))) uint32_t*)g,
                                   (__attribute__((address_space(3))) uint32_t*)l, 16, 0, 0);
}

// ------------------------------- fp32 -> bf16 ------------------------------
__global__ __launch_bounds__(256) void cvt_k(const float* __restrict__ src,
                                             short* __restrict__ dst, int n4) {
  int i = blockIdx.x * 256 + threadIdx.x;
  if (i < n4) {
    f32x4 v = *(const f32x4*)(src + (size_t)i * 4);
    bf16x4 o;
    o[0] = f2bf(v[0]); o[1] = f2bf(v[1]); o[2] = f2bf(v[2]); o[3] = f2bf(v[3]);
    *(bf16x4*)(dst + (size_t)i * 4) = o;
  }
}

// fused 4-weight convert: dst is contiguous (wqkv | wfcb), 1M elems each
__global__ __launch_bounds__(256) void cvtw_k(
    const float* __restrict__ w0, const float* __restrict__ w1,
    const float* __restrict__ w2, const float* __restrict__ w3,
    short* __restrict__ dst) {
  const int which = blockIdx.x >> 10;            // 1024 blocks per weight
  const float* src = which == 0 ? w0 : which == 1 ? w1 : which == 2 ? w2 : w3;
  const int i = (blockIdx.x & 1023) * 256 + threadIdx.x;   // < 262144
  f32x4 v = *(const f32x4*)(src + (size_t)i * 4);
  bf16x4 o;
  o[0] = f2bf(v[0]); o[1] = f2bf(v[1]); o[2] = f2bf(v[2]); o[3] = f2bf(v[3]);
  *(bf16x4*)(dst + (size_t)which * 1048576 + (size_t)i * 4) = o;
}

// ------------------------------- GEMM (NT) ---------------------------------
// C[M][N] = A[M][K] * B[N][K]^T.  128x64 tile, BK=32, 4 waves (2x2), each
// wave 64x32 = 4x2 MFMA frags.  EPI=0: scatter into fragment-linear Q/K/V
// with bias.  EPI=1: fp32 out [M][1024] with bias.  `rep` = idempotent
// re-execution count (profiling attribution).
template <int EPI>
__global__ __launch_bounds__(256) void gemm_k(
    const short* __restrict__ A, const short* __restrict__ B,
    const float* __restrict__ bq, const float* __restrict__ bk,
    const float* __restrict__ bv,
    short* __restrict__ Qb, short* __restrict__ Kb, short* __restrict__ Vt,
    float* __restrict__ Fout, int rep) {
  const int K = 1024;
  __shared__ short sA[128 * 32];
  __shared__ short sB[64 * 32];
  const int tid = threadIdx.x;
  const int w = tid >> 6, lane = tid & 63;
  const int wr = w >> 1, wc = w & 1;
  const int lrow = lane & 15, lk = (lane >> 4) * 8;
  const int tileM = blockIdx.x * 128, tileN = blockIdx.y * 64;

  for (int rp = 0; rp < rep; ++rp) {
    f32x4 acc[4][2];
#pragma unroll
    for (int i = 0; i < 4; ++i)
#pragma unroll
      for (int j = 0; j < 2; ++j) acc[i][j] = (f32x4){0.f, 0.f, 0.f, 0.f};

    for (int k0 = 0; k0 < K; k0 += 32) {
#pragma unroll
      for (int i = 0; i < 2; ++i) {
        int u = (w * 2 + i) * 64 + lane;     // 16B unit, 512 total
        int row = u >> 2, c8 = (u & 3) * 8;
        gload16(A + (size_t)(tileM + row) * K + k0 + c8, (short*)sA + (w * 2 + i) * 512);
      }
      {
        int u = w * 64 + lane;               // 16B unit, 256 total
        int row = u >> 2, c8 = (u & 3) * 8;
        gload16(B + (size_t)(tileN + row) * K + k0 + c8, (short*)sB + w * 512);
      }
      __syncthreads();
      bf16x8 af[4], bfr[2];
#pragma unroll
      for (int mi = 0; mi < 4; ++mi)
        af[mi] = *(const bf16x8*)&sA[(wr * 64 + mi * 16 + lrow) * 32 + lk];
#pragma unroll
      for (int ni = 0; ni < 2; ++ni)
        bfr[ni] = *(const bf16x8*)&sB[(wc * 32 + ni * 16 + lrow) * 32 + lk];
#pragma unroll
      for (int mi = 0; mi < 4; ++mi)
#pragma unroll
        for (int ni = 0; ni < 2; ++ni)
          acc[mi][ni] = MFMA16(af[mi], bfr[ni], acc[mi][ni]);
      __syncthreads();
    }

    // epilogue: D frag layout col = lane&15, row = (lane>>4)*4 + r
#pragma unroll
    for (int mi = 0; mi < 4; ++mi) {
      int m0 = tileM + wr * 64 + mi * 16 + (lane >> 4) * 4;
#pragma unroll
      for (int ni = 0; ni < 2; ++ni) {
        int n = tileN + wc * 32 + ni * 16 + lrow;
        f32x4 v = acc[mi][ni];
        if (EPI == 0) {
          int which = n >> 10, e = n & 1023;
          int h = e >> 6, dh = e & 63;
          float bias = (which == 0 ? bq : which == 1 ? bk : bv)[e];
          int b = m0 >> 11, s0 = m0 & 2047;  // s0 aligned to 4
          size_t hb = (size_t)(b * 16 + h);
          if (which == 2) {
            int kt2 = s0 >> 5, gl = (s0 >> 3) & 3, ni2 = dh >> 4, j = dh & 15;
            size_t base = (((hb * 64 + kt2) * 4 + ni2) * 64 + gl * 16 + j) * 8 + (s0 & 7);
            bf16x4 pk;
#pragma unroll
            for (int r = 0; r < 4; ++r) pk[r] = f2bf(v[r] + bias);
            *(bf16x4*)&Vt[base] = pk;
          } else {
            short* dst = (which == 0) ? Qb : Kb;
            int tile = s0 >> 4, h2 = dh >> 5, gl = (dh >> 3) & 3, ci = dh & 7;
            size_t base = (((hb * 128 + tile) * 2 + h2) * 64 + gl * 16 + (s0 & 15)) * 8 + ci;
#pragma unroll
            for (int r = 0; r < 4; ++r) dst[base + r * 8] = f2bf(v[r] + bias);
          }
        } else {
          float bias = bq[n];
#pragma unroll
          for (int r = 0; r < 4; ++r)
            Fout[(size_t)(m0 + r) * 1024 + n] = v[r] + bias;
        }
      }
    }
    __syncthreads();   // epilogue done before next rep's staging
  }
}

// ----------------------- attention pipeline helpers ------------------------
__device__ __forceinline__ void sw1_phase(bf16x8& pa, bf16x8& pb, int nxt,
    const short* __restrict__ Kf, int l8, const bf16x8& aQ0, const bf16x8& aQ1,
    float kscale, float& ls0, float& ls1, float& ls2, float& ls3) {
  const f32x4 zero = {0.f, 0.f, 0.f, 0.f};
  f32x4 s = MFMA16(pa, aQ0, zero);
  s = MFMA16(pb, aQ1, s);
  pa = *(const bf16x8*)&Kf[nxt * 1024 + l8];          // prefetch (reg rotate)
  pb = *(const bf16x8*)&Kf[nxt * 1024 + 512 + l8];
  ls0 += EXP2(s[0] * kscale);
  ls1 += EXP2(s[1] * kscale);
  ls2 += EXP2(s[2] * kscale);
  ls3 += EXP2(s[3] * kscale);
}

__device__ __forceinline__ void sw2_phase(
    bf16x8& k00, bf16x8& k01, bf16x8& k10, bf16x8& k11,
    bf16x8& v0, bf16x8& v1, bf16x8& v2, bf16x8& v3,
    int kt2, int nxt, short* __restrict__ wl,
    const short* __restrict__ Kw, const short* __restrict__ Vw, int l8,
    const bf16x8& aQ0, const bf16x8& aQ1, float rl, float kscale,
    float* __restrict__ Wqp, int lrow, int g,
    f32x4& o0, f32x4& o1, f32x4& o2, f32x4& o3) {
  const f32x4 zero = {0.f, 0.f, 0.f, 0.f};
  f32x4 sa = MFMA16(k00, aQ0, zero);
  sa = MFMA16(k01, aQ1, sa);
  f32x4 sb = MFMA16(k10, aQ0, zero);
  sb = MFMA16(k11, aQ1, sb);
  // prefetch next K tile-pair into the same named regs (after QK consume)
  const short* Ktn = &Kw[nxt * 2048];
  k00 = *(const bf16x8*)&Ktn[l8];
  k01 = *(const bf16x8*)&Ktn[512 + l8];
  k10 = *(const bf16x8*)&Ktn[1024 + l8];
  k11 = *(const bf16x8*)&Ktn[1536 + l8];
  f32x4 ea, eb;
#pragma unroll
  for (int r = 0; r < 4; ++r) ea[r] = EXP2(sa[r] * kscale) * rl;
#pragma unroll
  for (int r = 0; r < 4; ++r) eb[r] = EXP2(sb[r] * kscale) * rl;
  // weights: row q=lrow, cols kt2*32 + {0,16} + g*4 (vector stores)
  *(f32x4*)&Wqp[kt2 * 32] = ea;
  *(f32x4*)&Wqp[kt2 * 32 + 16] = eb;
  // P-tile via per-wave LDS (packed bf16), same-wave in-order DS pipe
  uint2 pa, pb;
  pa.x = cvtpk_bf16(ea[0], ea[1]);
  pa.y = cvtpk_bf16(ea[2], ea[3]);
  pb.x = cvtpk_bf16(eb[0], eb[1]);
  pb.y = cvtpk_bf16(eb[2], eb[3]);
  *(uint2*)&wl[lrow * 40 + g * 4] = pa;
  *(uint2*)&wl[lrow * 40 + 16 + g * 4] = pb;
  const bf16x8 aW = *(const bf16x8*)&wl[lrow * 40 + g * 8];
  o0 = MFMA16(aW, v0, o0);
  o1 = MFMA16(aW, v1, o1);
  o2 = MFMA16(aW, v2, o2);
  o3 = MFMA16(aW, v3, o3);
  // prefetch next V group (after PV consume)
  const short* Vpn = &Vw[nxt * 2048];
  v0 = *(const bf16x8*)&Vpn[l8];
  v1 = *(const bf16x8*)&Vpn[512 + l8];
  v2 = *(const bf16x8*)&Vpn[1024 + l8];
  v3 = *(const bf16x8*)&Vpn[1536 + l8];
}

// ------------------------------- attention ---------------------------------
// 1-D grid 1024: xcd = i&7 owns heads 4*xcd..4*xcd+3 (K/V L2-resident).
// bh = (i&7)*4 + (i>>3)&3, qt = i>>5.  Block = 64 q-rows of one head; wave
// w = 16 q-rows (qb = qt*4+w), full-K sweeps, swapped-operand QK^T, no
// barriers.  `rep` = idempotent re-execution count (profiling attribution).
__global__ __launch_bounds__(256, 4) void attn_k(
    const short* __restrict__ Qb, const short* __restrict__ Kb,
    const short* __restrict__ Vt, float* __restrict__ Wout,
    short* __restrict__ attn, int rep) {
  __shared__ short Wlds[4][2][16 * 40];   // [wave][phase] row stride 40 shorts
  const int i = blockIdx.x;
  const int bh = ((i & 7) << 2) | ((i >> 3) & 3);
  const int qt = i >> 5;
  const int w = threadIdx.x >> 6, lane = threadIdx.x & 63;
  const int lrow = lane & 15, g = lane >> 4;
  const int qb = qt * 4 + w;              // 16-row q-tile index within head
  const int l8 = lane * 8;
  const short* Qf = Qb + (size_t)(bh * 128 + qb) * 1024;
  const short* Kf = Kb + (size_t)bh * (128 * 1024);
  const short* Vf = Vt + (size_t)bh * (64 * 2048);
  const float kscale = 0.125f * 1.44269504088896f;  // 1/sqrt(64) / ln(2)
  const f32x4 zero = {0.f, 0.f, 0.f, 0.f};

  for (int rp = 0; rp < rep; ++rp) {
    const bf16x8 aQ0 = *(const bf16x8*)&Qf[l8];
    const bf16x8 aQ1 = *(const bf16x8*)&Qf[512 + l8];

    // ---- sweep 1: row sums of exp2, depth-4 named-register pipeline ----
    float ls0 = 0.f, ls1 = 0.f, ls2 = 0.f, ls3 = 0.f;
    bf16x8 p0a = *(const bf16x8*)&Kf[0 * 1024 + l8];
    bf16x8 p0b = *(const bf16x8*)&Kf[0 * 1024 + 512 + l8];
    bf16x8 p1a = *(const bf16x8*)&Kf[1 * 1024 + l8];
    bf16x8 p1b = *(const bf16x8*)&Kf[1 * 1024 + 512 + l8];
    bf16x8 p2a = *(const bf16x8*)&Kf[2 * 1024 + l8];
    bf16x8 p2b = *(const bf16x8*)&Kf[2 * 1024 + 512 + l8];
    bf16x8 p3a = *(const bf16x8*)&Kf[3 * 1024 + l8];
    bf16x8 p3b = *(const bf16x8*)&Kf[3 * 1024 + 512 + l8];
    for (int kt = 0; kt < 128; kt += 4) {
      sw1_phase(p0a, p0b, (kt + 4) & 127, Kf, l8, aQ0, aQ1, kscale, ls0, ls1, ls2, ls3);
      sw1_phase(p1a, p1b, (kt + 5) & 127, Kf, l8, aQ0, aQ1, kscale, ls0, ls1, ls2, ls3);
      sw1_phase(p2a, p2b, (kt + 6) & 127, Kf, l8, aQ0, aQ1, kscale, ls0, ls1, ls2, ls3);
      sw1_phase(p3a, p3b, (kt + 7) & 127, Kf, l8, aQ0, aQ1, kscale, ls0, ls1, ls2, ls3);
    }
    float lsum = (ls0 + ls1) + (ls2 + ls3);
    lsum += __shfl_xor(lsum, 16);
    lsum += __shfl_xor(lsum, 32);   // all lanes: full row-sum for q = lrow
    const float rl = 1.0f / lsum;

    // ---- sweep 2: weights out + PV, depth-2 named-register pipeline ----
    f32x4 o0 = zero, o1 = zero, o2 = zero, o3 = zero;
    float* Wqp = Wout + ((size_t)bh * 2048 + qb * 16 + lrow) * 2048 + g * 4;
    short* wlA = &Wlds[w][0][0];
    short* wlB = &Wlds[w][1][0];
    bf16x8 ka00 = *(const bf16x8*)&Kf[l8],        ka01 = *(const bf16x8*)&Kf[512 + l8];
    bf16x8 ka10 = *(const bf16x8*)&Kf[1024 + l8], ka11 = *(const bf16x8*)&Kf[1536 + l8];
    bf16x8 va0 = *(const bf16x8*)&Vf[l8],         va1 = *(const bf16x8*)&Vf[512 + l8];
    bf16x8 va2 = *(const bf16x8*)&Vf[1024 + l8],  va3 = *(const bf16x8*)&Vf[1536 + l8];
    bf16x8 kb00 = *(const bf16x8*)&Kf[2048 + l8], kb01 = *(const bf16x8*)&Kf[2560 + l8];
    bf16x8 kb10 = *(const bf16x8*)&Kf[3072 + l8], kb11 = *(const bf16x8*)&Kf[3584 + l8];
    bf16x8 vb0 = *(const bf16x8*)&Vf[2048 + l8],  vb1 = *(const bf16x8*)&Vf[2560 + l8];
    bf16x8 vb2 = *(const bf16x8*)&Vf[3072 + l8],  vb3 = *(const bf16x8*)&Vf[3584 + l8];
    for (int kt2 = 0; kt2 < 64; kt2 += 2) {
      sw2_phase(ka00, ka01, ka10, ka11, va0, va1, va2, va3,
                kt2, (kt2 + 2) & 63, wlA, Kf, Vf, l8, aQ0, aQ1, rl, kscale,
                Wqp, lrow, g, o0, o1, o2, o3);
      sw2_phase(kb00, kb01, kb10, kb11, vb0, vb1, vb2, vb3,
                kt2 + 1, (kt2 + 3) & 63, wlB, Kf, Vf, l8, aQ0, aQ1, rl, kscale,
                Wqp, lrow, g, o0, o1, o2, o3);
    }

    const int b = bh >> 4, h = bh & 15;
    const size_t obase = (size_t)(b * 2048 + qb * 16 + g * 4) * 1024 + h * 64 + lrow;
#pragma unroll
    for (int r = 0; r < 4; ++r) {
      attn[obase + (size_t)r * 1024 +  0] = f2bf(o0[r]);
      attn[obase + (size_t)r * 1024 + 16] = f2bf(o1[r]);
      attn[obase + (size_t)r * 1024 + 32] = f2bf(o2[r]);
      attn[obase + (size_t)r * 1024 + 48] = f2bf(o3[r]);
    }
  }
}

// ------------------------------- launch ------------------------------------
extern "C" void kernel_launch(void* const* d_in, const int* in_sizes, int n_in,
                              void* d_out, int out_size, void* d_ws,
                              size_t ws_size, hipStream_t stream) {
  const float* x   = (const float*)d_in[0];
  const float* Wq  = (const float*)d_in[1];
  const float* bq  = (const float*)d_in[2];
  const float* Wk  = (const float*)d_in[3];
  const float* bk  = (const float*)d_in[4];
  const float* Wv  = (const float*)d_in[5];
  const float* bv  = (const float*)d_in[6];
  const float* Wfc = (const float*)d_in[7];
  const float* bfc = (const float*)d_in[8];

  float* out  = (float*)d_out;                 // [2,2048,1024]
  float* wout = out + (size_t)4194304;         // [2,16,2048,2048]

  char* ws = (char*)d_ws;
  short* xb   = (short*)(ws);                  // 8 MB  (aliased: attn reuses it)
  short* wqkv = (short*)(ws + ((size_t)8  << 20));  // 6 MB: Wq|Wk|Wv rows
  short* wfcb = (short*)(ws + ((size_t)14 << 20));  // 2 MB (contig after wqkv)
  short* Qb   = (short*)(ws + ((size_t)16 << 20));  // 8 MB frag-linear
  short* Kb   = (short*)(ws + ((size_t)24 << 20));  // 8 MB frag-linear
  short* Vt   = (short*)(ws + ((size_t)32 << 20));  // 8 MB frag-linear
  short* attn = xb;                            // reuse after QKV GEMM reads xb

  // fp32 -> bf16 (x + fused 4-weight convert into contiguous wqkv|wfcb)
  cvt_k<<<4096, 256, 0, stream>>>(x, xb, 1048576);
  cvtw_k<<<4096, 256, 0, stream>>>(Wq, Wk, Wv, Wfc, wqkv);

  // QKV projection x12 (profiling): [4096,3072] = xb @ wqkv^T
  gemm_k<0><<<dim3(32, 48), 256, 0, stream>>>(xb, wqkv, bq, bk, bv, Qb, Kb, Vt,
                                              (float*)nullptr, 12);

  // attention x3 (profiling): 1-D grid 1024, XCD-pinned heads
  attn_k<<<dim3(1024), 256, 0, stream>>>(Qb, Kb, Vt, wout, attn, 3);

  // FC x30 (profiling): out = attn @ wfcb^T + bfc
  gemm_k<1><<<dim3(32, 16), 256, 0, stream>>>(attn, wfcb, bfc, nullptr, nullptr,
                                              nullptr, nullptr, nullptr, out, 30);
}

// Round 18
// 258.546 us; speedup vs baseline: 6.7568x; 6.7568x over previous
//
#include <hip/hip_runtime.h>
#include <hip/hip_bf16.h>
#include <stdint.h>

// ---------------------------------------------------------------------------
// Fused MHA block: QKV proj -> attention (weights are output[1]) -> FC proj
// B=2 S=2048 E=1024 H=16 Dh=64.  All matmuls bf16 MFMA 16x16x32, fp32 accum.
// r18 = r13 + DEFERRED WEIGHT STORES in sw2_phase.  r17's counters showed
// attn latency-bound with nothing saturated (Mfma 8%, VALU 14%, hbm 30%).
// Mechanism: vmcnt completes IN ISSUE ORDER; the weight stores were issued
// between K-prefetch and V-prefetch, so every PV's V-load wait transitively
// waited for the older, slow 537MB store stream to retire (consistent with
// r16's nt-store regression).  Moving the stores AFTER the V-prefetch makes
// every load group older than the stores -> no load-wait drains them.
// ---------------------------------------------------------------------------

typedef __attribute__((ext_vector_type(8))) short bf16x8;
typedef __attribute__((ext_vector_type(4))) short bf16x4;
typedef __attribute__((ext_vector_type(4))) float f32x4;

#define MFMA16(a, b, c) __builtin_amdgcn_mfma_f32_16x16x32_bf16(a, b, c, 0, 0, 0)
#define EXP2(x) __builtin_amdgcn_exp2f(x)

__device__ __forceinline__ short f2bf(float x) {
  uint32_t u = __builtin_bit_cast(uint32_t, x);
  u += 0x7FFFu + ((u >> 16) & 1u);   // round-to-nearest-even
  return (short)(u >> 16);
}

__device__ __forceinline__ uint32_t cvtpk_bf16(float lo, float hi) {
  uint32_t r;
  asm("v_cvt_pk_bf16_f32 %0, %1, %2" : "=v"(r) : "v"(lo), "v"(hi));
  return r;  // low 16 = lo, high 16 = hi
}

__device__ __forceinline__ void gload16(const void* g, void* l) {
  __builtin_amdgcn_global_load_lds((const __attribute__((address_space(1))) uint32_t*)g,
                                   (__attribute__((address_space(3))) uint32_t*)l, 16, 0, 0);
}

// ------------------------------- fp32 -> bf16 ------------------------------
__global__ __launch_bounds__(256) void cvt_k(const float* __restrict__ src,
                                             short* __restrict__ dst, int n4) {
  int i = blockIdx.x * 256 + threadIdx.x;
  if (i < n4) {
    f32x4 v = *(const f32x4*)(src + (size_t)i * 4);
    bf16x4 o;
    o[0] = f2bf(v[0]); o[1] = f2bf(v[1]); o[2] = f2bf(v[2]); o[3] = f2bf(v[3]);
    *(bf16x4*)(dst + (size_t)i * 4) = o;
  }
}

// fused 4-weight convert: dst is contiguous (wqkv | wfcb), 1M elems each
__global__ __launch_bounds__(256) void cvtw_k(
    const float* __restrict__ w0, const float* __restrict__ w1,
    const float* __restrict__ w2, const float* __restrict__ w3,
    short* __restrict__ dst) {
  const int which = blockIdx.x >> 10;            // 1024 blocks per weight
  const float* src = which == 0 ? w0 : which == 1 ? w1 : which == 2 ? w2 : w3;
  const int i = (blockIdx.x & 1023) * 256 + threadIdx.x;   // < 262144
  f32x4 v = *(const f32x4*)(src + (size_t)i * 4);
  bf16x4 o;
  o[0] = f2bf(v[0]); o[1] = f2bf(v[1]); o[2] = f2bf(v[2]); o[3] = f2bf(v[3]);
  *(bf16x4*)(dst + (size_t)which * 1048576 + (size_t)i * 4) = o;
}

// ------------------------------- GEMM (NT) ---------------------------------
// C[M][N] = A[M][K] * B[N][K]^T.  128x64 tile, BK=32, 4 waves (2x2), each
// wave 64x32 = 4x2 MFMA frags.  EPI=0: scatter into fragment-linear Q/K/V
// with bias.  EPI=1: fp32 out [M][1024] with bias.
template <int EPI>
__global__ __launch_bounds__(256) void gemm_k(
    const short* __restrict__ A, const short* __restrict__ B,
    const float* __restrict__ bq, const float* __restrict__ bk,
    const float* __restrict__ bv,
    short* __restrict__ Qb, short* __restrict__ Kb, short* __restrict__ Vt,
    float* __restrict__ Fout) {
  const int K = 1024;
  __shared__ short sA[128 * 32];
  __shared__ short sB[64 * 32];
  const int tid = threadIdx.x;
  const int w = tid >> 6, lane = tid & 63;
  const int wr = w >> 1, wc = w & 1;
  const int lrow = lane & 15, lk = (lane >> 4) * 8;
  const int tileM = blockIdx.x * 128, tileN = blockIdx.y * 64;

  f32x4 acc[4][2];
#pragma unroll
  for (int i = 0; i < 4; ++i)
#pragma unroll
    for (int j = 0; j < 2; ++j) acc[i][j] = (f32x4){0.f, 0.f, 0.f, 0.f};

  for (int k0 = 0; k0 < K; k0 += 32) {
#pragma unroll
    for (int i = 0; i < 2; ++i) {
      int u = (w * 2 + i) * 64 + lane;       // 16B unit, 512 total
      int row = u >> 2, c8 = (u & 3) * 8;
      gload16(A + (size_t)(tileM + row) * K + k0 + c8, (short*)sA + (w * 2 + i) * 512);
    }
    {
      int u = w * 64 + lane;                 // 16B unit, 256 total
      int row = u >> 2, c8 = (u & 3) * 8;
      gload16(B + (size_t)(tileN + row) * K + k0 + c8, (short*)sB + w * 512);
    }
    __syncthreads();
    bf16x8 af[4], bfr[2];
#pragma unroll
    for (int mi = 0; mi < 4; ++mi)
      af[mi] = *(const bf16x8*)&sA[(wr * 64 + mi * 16 + lrow) * 32 + lk];
#pragma unroll
    for (int ni = 0; ni < 2; ++ni)
      bfr[ni] = *(const bf16x8*)&sB[(wc * 32 + ni * 16 + lrow) * 32 + lk];
#pragma unroll
    for (int mi = 0; mi < 4; ++mi)
#pragma unroll
      for (int ni = 0; ni < 2; ++ni)
        acc[mi][ni] = MFMA16(af[mi], bfr[ni], acc[mi][ni]);
    __syncthreads();
  }

  // epilogue: D frag layout col = lane&15, row = (lane>>4)*4 + r
#pragma unroll
  for (int mi = 0; mi < 4; ++mi) {
    int m0 = tileM + wr * 64 + mi * 16 + (lane >> 4) * 4;
#pragma unroll
    for (int ni = 0; ni < 2; ++ni) {
      int n = tileN + wc * 32 + ni * 16 + lrow;
      f32x4 v = acc[mi][ni];
      if (EPI == 0) {
        int which = n >> 10, e = n & 1023;
        int h = e >> 6, dh = e & 63;
        float bias = (which == 0 ? bq : which == 1 ? bk : bv)[e];
        int b = m0 >> 11, s0 = m0 & 2047;   // s0 aligned to 4
        size_t hb = (size_t)(b * 16 + h);
        if (which == 2) {
          // V^T element (dh, s): kt2=s>>5, gl=(s>>3)&3, ci=s&7; ni2=dh>>4, j=dh&15
          int kt2 = s0 >> 5, gl = (s0 >> 3) & 3, ni2 = dh >> 4, j = dh & 15;
          size_t base = (((hb * 64 + kt2) * 4 + ni2) * 64 + gl * 16 + j) * 8 + (s0 & 7);
          bf16x4 pk;
#pragma unroll
          for (int r = 0; r < 4; ++r) pk[r] = f2bf(v[r] + bias);
          *(bf16x4*)&Vt[base] = pk;
        } else {
          // Q/K element (s, dh): tile=s>>4, lane=(gl*16 + (s&15)), ci=dh&7
          short* dst = (which == 0) ? Qb : Kb;
          int tile = s0 >> 4, h2 = dh >> 5, gl = (dh >> 3) & 3, ci = dh & 7;
          size_t base = (((hb * 128 + tile) * 2 + h2) * 64 + gl * 16 + (s0 & 15)) * 8 + ci;
#pragma unroll
          for (int r = 0; r < 4; ++r) dst[base + r * 8] = f2bf(v[r] + bias);
        }
      } else {
        float bias = bq[n];
#pragma unroll
        for (int r = 0; r < 4; ++r)
          Fout[(size_t)(m0 + r) * 1024 + n] = v[r] + bias;
      }
    }
  }
}

// ----------------------- attention pipeline helpers ------------------------
__device__ __forceinline__ void sw1_phase(bf16x8& pa, bf16x8& pb, int nxt,
    const short* __restrict__ Kf, int l8, const bf16x8& aQ0, const bf16x8& aQ1,
    float kscale, float& ls0, float& ls1, float& ls2, float& ls3) {
  const f32x4 zero = {0.f, 0.f, 0.f, 0.f};
  f32x4 s = MFMA16(pa, aQ0, zero);
  s = MFMA16(pb, aQ1, s);
  pa = *(const bf16x8*)&Kf[nxt * 1024 + l8];          // prefetch (reg rotate)
  pb = *(const bf16x8*)&Kf[nxt * 1024 + 512 + l8];
  ls0 += EXP2(s[0] * kscale);
  ls1 += EXP2(s[1] * kscale);
  ls2 += EXP2(s[2] * kscale);
  ls3 += EXP2(s[3] * kscale);
}

__device__ __forceinline__ void sw2_phase(
    bf16x8& k00, bf16x8& k01, bf16x8& k10, bf16x8& k11,
    bf16x8& v0, bf16x8& v1, bf16x8& v2, bf16x8& v3,
    int kt2, int nxt, short* __restrict__ wl,
    const short* __restrict__ Kw, const short* __restrict__ Vw, int l8,
    const bf16x8& aQ0, const bf16x8& aQ1, float rl, float kscale,
    float* __restrict__ Wqp, int lrow, int g,
    f32x4& o0, f32x4& o1, f32x4& o2, f32x4& o3) {
  const f32x4 zero = {0.f, 0.f, 0.f, 0.f};
  f32x4 sa = MFMA16(k00, aQ0, zero);
  sa = MFMA16(k01, aQ1, sa);
  f32x4 sb = MFMA16(k10, aQ0, zero);
  sb = MFMA16(k11, aQ1, sb);
  // prefetch next K tile-pair into the same named regs (after QK consume)
  const short* Ktn = &Kw[nxt * 2048];
  k00 = *(const bf16x8*)&Ktn[l8];
  k01 = *(const bf16x8*)&Ktn[512 + l8];
  k10 = *(const bf16x8*)&Ktn[1024 + l8];
  k11 = *(const bf16x8*)&Ktn[1536 + l8];
  f32x4 ea, eb;
#pragma unroll
  for (int r = 0; r < 4; ++r) ea[r] = EXP2(sa[r] * kscale) * rl;
#pragma unroll
  for (int r = 0; r < 4; ++r) eb[r] = EXP2(sb[r] * kscale) * rl;
  // P-tile via per-wave LDS (packed bf16), same-wave in-order DS pipe
  uint2 pa, pb;
  pa.x = cvtpk_bf16(ea[0], ea[1]);
  pa.y = cvtpk_bf16(ea[2], ea[3]);
  pb.x = cvtpk_bf16(eb[0], eb[1]);
  pb.y = cvtpk_bf16(eb[2], eb[3]);
  *(uint2*)&wl[lrow * 40 + g * 4] = pa;
  *(uint2*)&wl[lrow * 40 + 16 + g * 4] = pb;
  const bf16x8 aW = *(const bf16x8*)&wl[lrow * 40 + g * 8];
  o0 = MFMA16(aW, v0, o0);
  o1 = MFMA16(aW, v1, o1);
  o2 = MFMA16(aW, v2, o2);
  o3 = MFMA16(aW, v3, o3);
  // prefetch next V group (after PV consume)
  const short* Vpn = &Vw[nxt * 2048];
  v0 = *(const bf16x8*)&Vpn[l8];
  v1 = *(const bf16x8*)&Vpn[512 + l8];
  v2 = *(const bf16x8*)&Vpn[1024 + l8];
  v3 = *(const bf16x8*)&Vpn[1536 + l8];
  // DEFERRED weight stores — issued AFTER all of this phase's loads, so
  // they are always the YOUNGEST vmem ops: with in-order vmcnt completion,
  // no subsequent load-wait ever has to drain the 537MB store stream.
  *(f32x4*)&Wqp[kt2 * 32] = ea;
  *(f32x4*)&Wqp[kt2 * 32 + 16] = eb;
}

// ------------------------------- attention ---------------------------------
// 1-D grid 1024: xcd = i&7 owns heads 4*xcd..4*xcd+3 (K/V L2-resident).
// bh = (i&7)*4 + (i>>3)&3, qt = i>>5.  Block = 64 q-rows of one head; wave
// w = 16 q-rows (qb = qt*4+w), full-K sweeps, swapped-operand QK^T, no
// barriers.  (r13 structure + deferred weight stores.)
__global__ __launch_bounds__(256, 4) void attn_k(
    const short* __restrict__ Qb, const short* __restrict__ Kb,
    const short* __restrict__ Vt, float* __restrict__ Wout,
    short* __restrict__ attn) {
  __shared__ short Wlds[4][2][16 * 40];   // [wave][phase] row stride 40 shorts
  const int i = blockIdx.x;
  const int bh = ((i & 7) << 2) | ((i >> 3) & 3);
  const int qt = i >> 5;
  const int w = threadIdx.x >> 6, lane = threadIdx.x & 63;
  const int lrow = lane & 15, g = lane >> 4;
  const int qb = qt * 4 + w;              // 16-row q-tile index within head
  const int l8 = lane * 8;
  const short* Qf = Qb + (size_t)(bh * 128 + qb) * 1024;
  const short* Kf = Kb + (size_t)bh * (128 * 1024);
  const short* Vf = Vt + (size_t)bh * (64 * 2048);
  const float kscale = 0.125f * 1.44269504088896f;  // 1/sqrt(64) / ln(2)
  const f32x4 zero = {0.f, 0.f, 0.f, 0.f};

  const bf16x8 aQ0 = *(const bf16x8*)&Qf[l8];
  const bf16x8 aQ1 = *(const bf16x8*)&Qf[512 + l8];

  // ---- sweep 1: row sums of exp2, depth-4 named-register pipeline ----
  float ls0 = 0.f, ls1 = 0.f, ls2 = 0.f, ls3 = 0.f;
  bf16x8 p0a = *(const bf16x8*)&Kf[0 * 1024 + l8];
  bf16x8 p0b = *(const bf16x8*)&Kf[0 * 1024 + 512 + l8];
  bf16x8 p1a = *(const bf16x8*)&Kf[1 * 1024 + l8];
  bf16x8 p1b = *(const bf16x8*)&Kf[1 * 1024 + 512 + l8];
  bf16x8 p2a = *(const bf16x8*)&Kf[2 * 1024 + l8];
  bf16x8 p2b = *(const bf16x8*)&Kf[2 * 1024 + 512 + l8];
  bf16x8 p3a = *(const bf16x8*)&Kf[3 * 1024 + l8];
  bf16x8 p3b = *(const bf16x8*)&Kf[3 * 1024 + 512 + l8];
  for (int kt = 0; kt < 128; kt += 4) {
    sw1_phase(p0a, p0b, (kt + 4) & 127, Kf, l8, aQ0, aQ1, kscale, ls0, ls1, ls2, ls3);
    sw1_phase(p1a, p1b, (kt + 5) & 127, Kf, l8, aQ0, aQ1, kscale, ls0, ls1, ls2, ls3);
    sw1_phase(p2a, p2b, (kt + 6) & 127, Kf, l8, aQ0, aQ1, kscale, ls0, ls1, ls2, ls3);
    sw1_phase(p3a, p3b, (kt + 7) & 127, Kf, l8, aQ0, aQ1, kscale, ls0, ls1, ls2, ls3);
  }
  float lsum = (ls0 + ls1) + (ls2 + ls3);
  lsum += __shfl_xor(lsum, 16);
  lsum += __shfl_xor(lsum, 32);   // all lanes: full row-sum for q = lrow
  const float rl = 1.0f / lsum;

  // ---- sweep 2: weights out + PV, depth-2 named-register pipeline ----
  f32x4 o0 = zero, o1 = zero, o2 = zero, o3 = zero;
  float* Wqp = Wout + ((size_t)bh * 2048 + qb * 16 + lrow) * 2048 + g * 4;
  short* wlA = &Wlds[w][0][0];
  short* wlB = &Wlds[w][1][0];
  // prologue: buffers A <- kt2=0, B <- kt2=1
  bf16x8 ka00 = *(const bf16x8*)&Kf[l8],        ka01 = *(const bf16x8*)&Kf[512 + l8];
  bf16x8 ka10 = *(const bf16x8*)&Kf[1024 + l8], ka11 = *(const bf16x8*)&Kf[1536 + l8];
  bf16x8 va0 = *(const bf16x8*)&Vf[l8],         va1 = *(const bf16x8*)&Vf[512 + l8];
  bf16x8 va2 = *(const bf16x8*)&Vf[1024 + l8],  va3 = *(const bf16x8*)&Vf[1536 + l8];
  bf16x8 kb00 = *(const bf16x8*)&Kf[2048 + l8], kb01 = *(const bf16x8*)&Kf[2560 + l8];
  bf16x8 kb10 = *(const bf16x8*)&Kf[3072 + l8], kb11 = *(const bf16x8*)&Kf[3584 + l8];
  bf16x8 vb0 = *(const bf16x8*)&Vf[2048 + l8],  vb1 = *(const bf16x8*)&Vf[2560 + l8];
  bf16x8 vb2 = *(const bf16x8*)&Vf[3072 + l8],  vb3 = *(const bf16x8*)&Vf[3584 + l8];
  for (int kt2 = 0; kt2 < 64; kt2 += 2) {
    sw2_phase(ka00, ka01, ka10, ka11, va0, va1, va2, va3,
              kt2, (kt2 + 2) & 63, wlA, Kf, Vf, l8, aQ0, aQ1, rl, kscale,
              Wqp, lrow, g, o0, o1, o2, o3);
    sw2_phase(kb00, kb01, kb10, kb11, vb0, vb1, vb2, vb3,
              kt2 + 1, (kt2 + 3) & 63, wlB, Kf, Vf, l8, aQ0, aQ1, rl, kscale,
              Wqp, lrow, g, o0, o1, o2, o3);
  }

  const int b = bh >> 4, h = bh & 15;
  const size_t obase = (size_t)(b * 2048 + qb * 16 + g * 4) * 1024 + h * 64 + lrow;
#pragma unroll
  for (int r = 0; r < 4; ++r) {
    attn[obase + (size_t)r * 1024 +  0] = f2bf(o0[r]);
    attn[obase + (size_t)r * 1024 + 16] = f2bf(o1[r]);
    attn[obase + (size_t)r * 1024 + 32] = f2bf(o2[r]);
    attn[obase + (size_t)r * 1024 + 48] = f2bf(o3[r]);
  }
}

// ------------------------------- launch ------------------------------------
extern "C" void kernel_launch(void* const* d_in, const int* in_sizes, int n_in,
                              void* d_out, int out_size, void* d_ws,
                              size_t ws_size, hipStream_t stream) {
  const float* x   = (const float*)d_in[0];
  const float* Wq  = (const float*)d_in[1];
  const float* bq  = (const float*)d_in[2];
  const float* Wk  = (const float*)d_in[3];
  const float* bk  = (const float*)d_in[4];
  const float* Wv  = (const float*)d_in[5];
  const float* bv  = (const float*)d_in[6];
  const float* Wfc = (const float*)d_in[7];
  const float* bfc = (const float*)d_in[8];

  float* out  = (float*)d_out;                 // [2,2048,1024]
  float* wout = out + (size_t)4194304;         // [2,16,2048,2048]

  char* ws = (char*)d_ws;
  short* xb   = (short*)(ws);                  // 8 MB  (aliased: attn reuses it)
  short* wqkv = (short*)(ws + ((size_t)8  << 20));  // 6 MB: Wq|Wk|Wv rows
  short* wfcb = (short*)(ws + ((size_t)14 << 20));  // 2 MB (contig after wqkv)
  short* Qb   = (short*)(ws + ((size_t)16 << 20));  // 8 MB frag-linear
  short* Kb   = (short*)(ws + ((size_t)24 << 20));  // 8 MB frag-linear
  short* Vt   = (short*)(ws + ((size_t)32 << 20));  // 8 MB frag-linear
  short* attn = xb;                            // reuse after QKV GEMM reads xb

  // fp32 -> bf16 (x + fused 4-weight convert into contiguous wqkv|wfcb)
  cvt_k<<<4096, 256, 0, stream>>>(x, xb, 1048576);
  cvtw_k<<<4096, 256, 0, stream>>>(Wq, Wk, Wv, Wfc, wqkv);

  // QKV projection: [4096,3072] = xb[4096,1024] @ wqkv[3072,1024]^T
  gemm_k<0><<<dim3(32, 48), 256, 0, stream>>>(xb, wqkv, bq, bk, bv, Qb, Kb, Vt,
                                              (float*)nullptr);

  // attention: 1-D grid 1024, XCD-pinned heads, deferred weight stores
  attn_k<<<dim3(1024), 256, 0, stream>>>(Qb, Kb, Vt, wout, attn);

  // FC: out[4096,1024] = attn[4096,1024] @ wfcb[1024,1024]^T + bfc
  gemm_k<1><<<dim3(32, 16), 256, 0, stream>>>(attn, wfcb, bfc, nullptr, nullptr,
                                              nullptr, nullptr, nullptr, out);
}